// Round 16
// baseline (296.579 us; speedup 1.0000x reference)
//
#include <hip/hip_runtime.h>

typedef unsigned short ushort_t;
typedef __bf16 bf16x8 __attribute__((ext_vector_type(8)));
typedef ushort_t u16x8 __attribute__((ext_vector_type(8)));
typedef float f32x4 __attribute__((ext_vector_type(4)));

#define DEVI __device__ __forceinline__

// Problem dims
constexpr int Ed = 1024;   // embed
constexpr int Hh = 16;     // heads
constexpr int Dd = 64;     // head dim
constexpr int Ss = 2048;   // seq
constexpr int Mm = 4096;   // B*S rows

constexpr int NX4 = Mm * Ed / 4;
constexpr int NW4 = Ed * Ed / 4;

DEVI ushort_t f2bf(float f) {      // RNE (cold paths only)
    union { float f; unsigned int i; } v; v.f = f;
    unsigned int r = v.i + 0x7fffu + ((v.i >> 16) & 1u);
    return (ushort_t)(r >> 16);
}
DEVI ushort_t f2bf_hi(float f) {   // truncation: compiles to *_d16_hi store, 0 VALU
    union { float f; unsigned int i; } v; v.f = f;
    return (ushort_t)(v.i >> 16);
}

// One-shot fp32 -> bf16 conversion of x + 4 weight matrices (RNE).
__global__ __launch_bounds__(256) void cvt_all(
    const float* __restrict__ x,  const float* __restrict__ Wq,
    const float* __restrict__ Wk, const float* __restrict__ Wv,
    const float* __restrict__ Wo,
    ushort_t* __restrict__ xb,  ushort_t* __restrict__ Wqb,
    ushort_t* __restrict__ Wkb, ushort_t* __restrict__ Wvb,
    ushort_t* __restrict__ Wob)
{
    int i = blockIdx.x * 256 + threadIdx.x;
    const float* s; ushort_t* d; int off;
    if (i < NX4)                { s = x;  d = xb;  off = i; }
    else if (i < NX4 + NW4)     { s = Wq; d = Wqb; off = i - NX4; }
    else if (i < NX4 + 2 * NW4) { s = Wk; d = Wkb; off = i - NX4 - NW4; }
    else if (i < NX4 + 3 * NW4) { s = Wv; d = Wvb; off = i - NX4 - 2 * NW4; }
    else                        { s = Wo; d = Wob; off = i - NX4 - 3 * NW4; }
    float4 v = ((const float4*)s)[off];
    ushort4 o; o.x = f2bf(v.x); o.y = f2bf(v.y); o.z = f2bf(v.z); o.w = f2bf(v.w);
    ((ushort4*)d)[off] = o;
}

// async global->LDS, 16B per lane
DEVI void gld16(const void* g, void* l) {
    __builtin_amdgcn_global_load_lds(
        (__attribute__((address_space(1))) void*)(g),
        (__attribute__((address_space(3))) void*)(l), 16, 0, 0);
}

// ---------------- NT GEMM core (m97 pattern) ----------------
DEVI void gemm_core(const ushort_t* __restrict__ A, const ushort_t* __restrict__ W,
                    ushort_t* As, ushort_t* Bs, int tm, int tn, int K,
                    f32x4 acc[4][4])
{
    const int tid  = threadIdx.x;
    const int w    = tid >> 6;
    const int lane = tid & 63;
    const int quad = lane >> 4;
    const int l15  = lane & 15;
    const int wy   = w >> 1, wx = w & 1;
    const int rowc = lane >> 3;
    const int col8 = (lane & 7) * 8;

    for (int k0 = 0; k0 < K; k0 += 64) {
        __syncthreads();
#pragma unroll
        for (int i = 0; i < 4; ++i) {
            int chunk = w * 4 + i;
            int row = chunk * 8 + rowc;
            gld16(A + (size_t)(tm + row) * K + k0 + col8, (char*)As + chunk * 1024);
            gld16(W + (size_t)(tn + row) * K + k0 + col8, (char*)Bs + chunk * 1024);
        }
        __syncthreads();
#pragma unroll
        for (int ks = 0; ks < 64; ks += 32) {
            bf16x8 a[4], b[4];
#pragma unroll
            for (int mi = 0; mi < 4; ++mi)
                a[mi] = *(const bf16x8*)&As[(wy * 64 + mi * 16 + l15) * 64 + ks + quad * 8];
#pragma unroll
            for (int ni = 0; ni < 4; ++ni)
                b[ni] = *(const bf16x8*)&Bs[(wx * 64 + ni * 16 + l15) * 64 + ks + quad * 8];
#pragma unroll
            for (int mi = 0; mi < 4; ++mi)
#pragma unroll
                for (int ni = 0; ni < 4; ++ni)
                    acc[mi][ni] = __builtin_amdgcn_mfma_f32_16x16x32_bf16(
                        a[mi], b[ni], acc[mi][ni], 0, 0, 0);
        }
    }
}

// Fused QKV projection. Q,K stored [B,H,S,D]; V stored [B,H,D,S].
__global__ __launch_bounds__(256, 3) void qkv_gemm(
    const ushort_t* __restrict__ x,
    const ushort_t* __restrict__ Wq, const float* __restrict__ bq,
    const ushort_t* __restrict__ Wk, const float* __restrict__ bk,
    const ushort_t* __restrict__ Wv, const float* __restrict__ bv,
    ushort_t* __restrict__ qo, ushort_t* __restrict__ ko, ushort_t* __restrict__ vto)
{
    __shared__ __align__(16) ushort_t As[128 * 64];
    __shared__ __align__(16) ushort_t Bs[128 * 64];
    const ushort_t* W; const float* bias; ushort_t* outp; int vmode;
    if (blockIdx.z == 0)      { W = Wq; bias = bq; outp = qo;  vmode = 0; }
    else if (blockIdx.z == 1) { W = Wk; bias = bk; outp = ko;  vmode = 0; }
    else                      { W = Wv; bias = bv; outp = vto; vmode = 1; }

    const int tm = blockIdx.x * 128, tn = blockIdx.y * 128;
    f32x4 acc[4][4] = {};
    gemm_core(x, W, As, Bs, tm, tn, Ed, acc);

    const int tid = threadIdx.x, w = tid >> 6, lane = tid & 63;
    const int quad = lane >> 4, l15 = lane & 15;
    const int wy = w >> 1, wx = w & 1;
#pragma unroll
    for (int ni = 0; ni < 4; ++ni) {
        int gc = tn + wx * 64 + ni * 16 + l15;
        float bb = bias[gc];
        int h = gc >> 6, d = gc & 63;
#pragma unroll
        for (int mi = 0; mi < 4; ++mi) {
#pragma unroll
            for (int r = 0; r < 4; ++r) {
                int gr = tm + wy * 64 + mi * 16 + quad * 4 + r;
                int b_ = gr >> 11, s_ = gr & 2047;
                float v = acc[mi][ni][r] + bb;
                size_t addr;
                if (vmode == 0) addr = ((size_t)(b_ * Hh + h) * Ss + s_) * Dd + d;
                else            addr = ((size_t)(b_ * Hh + h) * Dd + d) * Ss + s_;
                outp[addr] = f2bf_hi(v);
            }
        }
    }
}

// Output projection: out = ctx @ Wo^T + bo, [M,E] FP32. Penalty fused in block (0,0).
__global__ __launch_bounds__(256, 3) void out_gemm(
    const ushort_t* __restrict__ ctx, const ushort_t* __restrict__ Wo,
    const float* __restrict__ bo, const float* __restrict__ z,
    float* __restrict__ out)
{
    __shared__ __align__(16) ushort_t As[128 * 64];
    __shared__ __align__(16) ushort_t Bs[64 * 64];
    const int tm = blockIdx.x * 128, tn = blockIdx.y * 64;

    const int tid  = threadIdx.x;
    const int w    = tid >> 6;
    const int lane = tid & 63;
    const int quad = lane >> 4;
    const int l15  = lane & 15;
    const int wy   = w >> 1, wx = w & 1;
    const int rowc = lane >> 3;
    const int col8 = (lane & 7) * 8;

    f32x4 acc[4][2] = {};
    for (int k0 = 0; k0 < Ed; k0 += 64) {
        __syncthreads();
#pragma unroll
        for (int i = 0; i < 4; ++i) {
            int chunk = w * 4 + i;
            int row = chunk * 8 + rowc;
            gld16(ctx + (size_t)(tm + row) * Ed + k0 + col8, (char*)As + chunk * 1024);
        }
#pragma unroll
        for (int i = 0; i < 2; ++i) {
            int chunk = w * 2 + i;
            int row = chunk * 8 + rowc;
            gld16(Wo + (size_t)(tn + row) * Ed + k0 + col8, (char*)Bs + chunk * 1024);
        }
        __syncthreads();
#pragma unroll
        for (int ks = 0; ks < 64; ks += 32) {
            bf16x8 a[4], b[2];
#pragma unroll
            for (int mi = 0; mi < 4; ++mi)
                a[mi] = *(const bf16x8*)&As[(wy * 64 + mi * 16 + l15) * 64 + ks + quad * 8];
#pragma unroll
            for (int ni = 0; ni < 2; ++ni)
                b[ni] = *(const bf16x8*)&Bs[(wx * 32 + ni * 16 + l15) * 64 + ks + quad * 8];
#pragma unroll
            for (int mi = 0; mi < 4; ++mi)
#pragma unroll
                for (int ni = 0; ni < 2; ++ni)
                    acc[mi][ni] = __builtin_amdgcn_mfma_f32_16x16x32_bf16(
                        a[mi], b[ni], acc[mi][ni], 0, 0, 0);
        }
    }

#pragma unroll
    for (int ni = 0; ni < 2; ++ni) {
        int gc = tn + wx * 32 + ni * 16 + l15;
        float bb = bo[gc];
#pragma unroll
        for (int mi = 0; mi < 4; ++mi)
#pragma unroll
            for (int r = 0; r < 4; ++r) {
                int gr = tm + wy * 64 + mi * 16 + quad * 4 + r;
                out[(size_t)gr * Ed + gc] = acc[mi][ni][r] + bb;
            }
    }

    if (blockIdx.x == 0 && blockIdx.y == 0 && tid == 0) {
        float s = 0.f;
        for (int hh = 0; hh < Hh; ++hh) s += 1.f / (1.f + __expf(-z[hh]));
        out[(size_t)Mm * Ed] = s * 0.01f;
    }
}

// Flash attention v16: R14 geometry (64 q-rows, 4 waves x 16 rows, 4 blocks/CU)
// + V in REGISTERS (loads issued alongside K staging; the staging barrier's
// vmcnt(0) drains both concurrently -> no extra exposed latency, unlike R12
// which also dropped occupancy). Removes 8/18 ds_read_b128 and 8KB V staging.
// grid = (S/64, B*H) = (32, 32) = 1024 blocks.
__global__ __launch_bounds__(256, 4) void attn(
    const ushort_t* __restrict__ Q, const ushort_t* __restrict__ Kk,
    const ushort_t* __restrict__ Vt, const float* __restrict__ z,
    ushort_t* __restrict__ ctx)
{
    __shared__ __align__(16) ushort_t Ks[64 * 64];     // swizzled [key][d]
    __shared__ __align__(16) ushort_t Ps[4][16 * 68];  // per-wave P scratch

    const int tid = threadIdx.x, w = tid >> 6, lane = tid & 63;
    const int quad = lane >> 4, l15 = lane & 15;
    const int qt = blockIdx.x;           // 0..31
    const int bh = blockIdx.y;           // 0..31
    const int h = bh & (Hh - 1), b_ = bh >> 4;
    const size_t base = (size_t)bh * Ss * Dd;

    const float gate = 1.f / (1.f + __expf(-z[h]));
    const float scl2 = gate * 0.125f * 1.44269504f;  // gate/sqrt(D) * log2(e)

    bf16x8 aQ[2];
#pragma unroll
    for (int c = 0; c < 2; ++c)
        aQ[c] = *(const bf16x8*)&Q[base + (size_t)(qt * 64 + w * 16 + l15) * Dd
                                   + c * 32 + quad * 8];

    // K staging swizzle (R11/R14 pattern)
    const int rowA = w * 16 + (lane >> 3);
    const int rowB = rowA + 8;
    const int gsA  = (lane & 7) ^ (rowA & 7);
    const int gsB  = (lane & 7) ^ (rowB & 7);
    const ushort_t* kSrcA = Kk + base + (size_t)rowA * Dd + gsA * 8;
    const ushort_t* kSrcB = Kk + base + (size_t)rowB * Dd + gsB * 8;
    ushort_t* kDstA = Ks + (w * 2) * 512;
    ushort_t* kDstB = Ks + (w * 2 + 1) * 512;

    f32x4 accO[4] = {};
    float lsum[4] = {0.f, 0.f, 0.f, 0.f};

    const int swq = (l15 & 7) * 8;

    for (int kt = 0; kt < Ss / 64; ++kt) {
        __syncthreads();   // prior Ks readers done
        gld16(kSrcA + (size_t)kt * 64 * Dd, kDstA);
        gld16(kSrcB + (size_t)kt * 64 * Dd, kDstB);
        // V fragments -> registers; in flight concurrently with K staging,
        // both drained by the same vmcnt(0) at the barrier below.
        bf16x8 bV[4][2];
#pragma unroll
        for (int ni = 0; ni < 4; ++ni)
#pragma unroll
            for (int c = 0; c < 2; ++c)
                bV[ni][c] = *(const bf16x8*)&Vt[base
                    + (size_t)(ni * 16 + l15) * Ss + kt * 64 + c * 32 + quad * 8];
        __syncthreads();   // K staged + V regs ready

        // S = Q K^T (16 q-rows x 64 keys)
        f32x4 sAcc[4] = {};
#pragma unroll
        for (int ni = 0; ni < 4; ++ni) {
            bf16x8 b0 = *(const bf16x8*)&Ks[(ni * 16 + l15) * 64 + ((quad * 8) ^ swq)];
            bf16x8 b1 = *(const bf16x8*)&Ks[(ni * 16 + l15) * 64 + (((quad + 4) * 8) ^ swq)];
            sAcc[ni] = __builtin_amdgcn_mfma_f32_16x16x32_bf16(aQ[0], b0, sAcc[ni], 0, 0, 0);
            sAcc[ni] = __builtin_amdgcn_mfma_f32_16x16x32_bf16(aQ[1], b1, sAcc[ni], 0, 0, 0);
        }

        // p = 2^(s*scl2); per-lane row sums; P -> per-wave LDS (C->A transpose)
#pragma unroll
        for (int ni = 0; ni < 4; ++ni)
#pragma unroll
            for (int r = 0; r < 4; ++r) {
                float p = exp2f(sAcc[ni][r] * scl2);
                lsum[r] += p;
                Ps[w][(quad * 4 + r) * 68 + ni * 16 + l15] = f2bf_hi(p);
            }

        // O += P V  (A = P from LDS, B = V registers)
#pragma unroll
        for (int c = 0; c < 2; ++c) {
            bf16x8 aP = *(const bf16x8*)&Ps[w][l15 * 68 + c * 32 + quad * 8];
#pragma unroll
            for (int ni = 0; ni < 4; ++ni)
                accO[ni] = __builtin_amdgcn_mfma_f32_16x16x32_bf16(
                    aP, bV[ni][c], accO[ni], 0, 0, 0);
        }
    }

#pragma unroll
    for (int r = 0; r < 4; ++r) {
        lsum[r] += __shfl_xor(lsum[r], 1);
        lsum[r] += __shfl_xor(lsum[r], 2);
        lsum[r] += __shfl_xor(lsum[r], 4);
        lsum[r] += __shfl_xor(lsum[r], 8);
    }

#pragma unroll
    for (int r = 0; r < 4; ++r) {
        int srow = qt * 64 + w * 16 + quad * 4 + r;
        float inv = 1.f / lsum[r];
#pragma unroll
        for (int ni = 0; ni < 4; ++ni) {
            int d = ni * 16 + l15;
            ctx[((size_t)(b_ * Ss + srow)) * Ed + h * Dd + d] = f2bf_hi(accO[ni][r] * inv);
        }
    }
}

extern "C" void kernel_launch(void* const* d_in, const int* in_sizes, int n_in,
                              void* d_out, int out_size, void* d_ws, size_t ws_size,
                              hipStream_t stream) {
    const float* x  = (const float*)d_in[0];
    const float* Wq = (const float*)d_in[1];
    const float* bq = (const float*)d_in[2];
    const float* Wk = (const float*)d_in[3];
    const float* bk = (const float*)d_in[4];
    const float* Wv = (const float*)d_in[5];
    const float* bv = (const float*)d_in[6];
    const float* Wo = (const float*)d_in[7];
    const float* bo = (const float*)d_in[8];
    const float* z  = (const float*)d_in[9];
    float* out = (float*)d_out;

    ushort_t* xb  = (ushort_t*)d_ws;              // [M,E]     8 MB
    ushort_t* Wqb = xb  + (size_t)Mm * Ed;        // [E,E]     2 MB
    ushort_t* Wkb = Wqb + (size_t)Ed * Ed;
    ushort_t* Wvb = Wkb + (size_t)Ed * Ed;
    ushort_t* Wob = Wvb + (size_t)Ed * Ed;
    ushort_t* qw  = Wob + (size_t)Ed * Ed;        // [B,H,S,D] 8 MB
    ushort_t* kw  = qw + (size_t)Mm * Ed;         // [B,H,S,D] 8 MB
    ushort_t* vT  = kw + (size_t)Mm * Ed;         // [B,H,D,S] 8 MB
    ushort_t* cx  = vT + (size_t)Mm * Ed;         // [B,S,E]   8 MB

    dim3 blk(256);
    cvt_all<<<dim3((NX4 + 4 * NW4) / 256), blk, 0, stream>>>(
        x, Wq, Wk, Wv, Wo, xb, Wqb, Wkb, Wvb, Wob);
    qkv_gemm<<<dim3(Mm / 128, Ed / 128, 3), blk, 0, stream>>>(
        xb, Wqb, bq, Wkb, bk, Wvb, bv, qw, kw, vT);
    attn<<<dim3(Ss / 64, 2 * Hh), blk, 0, stream>>>(qw, kw, vT, z, cx);
    out_gemm<<<dim3(Mm / 128, Ed / 64), blk, 0, stream>>>(cx, Wob, bo, z, out);
}

// Round 17
// 214.684 us; speedup vs baseline: 1.3815x; 1.3815x over previous
//
#include <hip/hip_runtime.h>

typedef unsigned short ushort_t;
typedef __bf16 bf16x8 __attribute__((ext_vector_type(8)));
typedef ushort_t u16x8 __attribute__((ext_vector_type(8)));
typedef float f32x4 __attribute__((ext_vector_type(4)));

#define DEVI __device__ __forceinline__

// Problem dims
constexpr int Ed = 1024;   // embed
constexpr int Hh = 16;     // heads
constexpr int Dd = 64;     // head dim
constexpr int Ss = 2048;   // seq
constexpr int Mm = 4096;   // B*S rows

constexpr int NX4 = Mm * Ed / 4;
constexpr int NW4 = Ed * Ed / 4;

DEVI ushort_t f2bf(float f) {      // RNE (cold paths only)
    union { float f; unsigned int i; } v; v.f = f;
    unsigned int r = v.i + 0x7fffu + ((v.i >> 16) & 1u);
    return (ushort_t)(r >> 16);
}
DEVI ushort_t f2bf_hi(float f) {   // truncation: compiles to *_d16_hi store, 0 VALU
    union { float f; unsigned int i; } v; v.f = f;
    return (ushort_t)(v.i >> 16);
}
DEVI float fast_exp2(float x) {    // raw v_exp_f32 (no ocml wrapper)
    float r;
    asm("v_exp_f32 %0, %1" : "=v"(r) : "v"(x));
    return r;
}

// One-shot fp32 -> bf16 conversion of x + 4 weight matrices (RNE).
__global__ __launch_bounds__(256) void cvt_all(
    const float* __restrict__ x,  const float* __restrict__ Wq,
    const float* __restrict__ Wk, const float* __restrict__ Wv,
    const float* __restrict__ Wo,
    ushort_t* __restrict__ xb,  ushort_t* __restrict__ Wqb,
    ushort_t* __restrict__ Wkb, ushort_t* __restrict__ Wvb,
    ushort_t* __restrict__ Wob)
{
    int i = blockIdx.x * 256 + threadIdx.x;
    const float* s; ushort_t* d; int off;
    if (i < NX4)                { s = x;  d = xb;  off = i; }
    else if (i < NX4 + NW4)     { s = Wq; d = Wqb; off = i - NX4; }
    else if (i < NX4 + 2 * NW4) { s = Wk; d = Wkb; off = i - NX4 - NW4; }
    else if (i < NX4 + 3 * NW4) { s = Wv; d = Wvb; off = i - NX4 - 2 * NW4; }
    else                        { s = Wo; d = Wob; off = i - NX4 - 3 * NW4; }
    float4 v = ((const float4*)s)[off];
    ushort4 o; o.x = f2bf(v.x); o.y = f2bf(v.y); o.z = f2bf(v.z); o.w = f2bf(v.w);
    ((ushort4*)d)[off] = o;
}

// async global->LDS, 16B per lane
DEVI void gld16(const void* g, void* l) {
    __builtin_amdgcn_global_load_lds(
        (__attribute__((address_space(1))) void*)(g),
        (__attribute__((address_space(3))) void*)(l), 16, 0, 0);
}

// ---------------- NT GEMM core (m97 pattern) ----------------
DEVI void gemm_core(const ushort_t* __restrict__ A, const ushort_t* __restrict__ W,
                    ushort_t* As, ushort_t* Bs, int tm, int tn, int K,
                    f32x4 acc[4][4])
{
    const int tid  = threadIdx.x;
    const int w    = tid >> 6;
    const int lane = tid & 63;
    const int quad = lane >> 4;
    const int l15  = lane & 15;
    const int wy   = w >> 1, wx = w & 1;
    const int rowc = lane >> 3;
    const int col8 = (lane & 7) * 8;

    for (int k0 = 0; k0 < K; k0 += 64) {
        __syncthreads();
#pragma unroll
        for (int i = 0; i < 4; ++i) {
            int chunk = w * 4 + i;
            int row = chunk * 8 + rowc;
            gld16(A + (size_t)(tm + row) * K + k0 + col8, (char*)As + chunk * 1024);
            gld16(W + (size_t)(tn + row) * K + k0 + col8, (char*)Bs + chunk * 1024);
        }
        __syncthreads();
#pragma unroll
        for (int ks = 0; ks < 64; ks += 32) {
            bf16x8 a[4], b[4];
#pragma unroll
            for (int mi = 0; mi < 4; ++mi)
                a[mi] = *(const bf16x8*)&As[(wy * 64 + mi * 16 + l15) * 64 + ks + quad * 8];
#pragma unroll
            for (int ni = 0; ni < 4; ++ni)
                b[ni] = *(const bf16x8*)&Bs[(wx * 64 + ni * 16 + l15) * 64 + ks + quad * 8];
#pragma unroll
            for (int mi = 0; mi < 4; ++mi)
#pragma unroll
                for (int ni = 0; ni < 4; ++ni)
                    acc[mi][ni] = __builtin_amdgcn_mfma_f32_16x16x32_bf16(
                        a[mi], b[ni], acc[mi][ni], 0, 0, 0);
        }
    }
}

// Fused QKV projection. Q,K stored [B,H,S,D]; V stored [B,H,D,S].
__global__ __launch_bounds__(256, 3) void qkv_gemm(
    const ushort_t* __restrict__ x,
    const ushort_t* __restrict__ Wq, const float* __restrict__ bq,
    const ushort_t* __restrict__ Wk, const float* __restrict__ bk,
    const ushort_t* __restrict__ Wv, const float* __restrict__ bv,
    ushort_t* __restrict__ qo, ushort_t* __restrict__ ko, ushort_t* __restrict__ vto)
{
    __shared__ __align__(16) ushort_t As[128 * 64];
    __shared__ __align__(16) ushort_t Bs[128 * 64];
    const ushort_t* W; const float* bias; ushort_t* outp; int vmode;
    if (blockIdx.z == 0)      { W = Wq; bias = bq; outp = qo;  vmode = 0; }
    else if (blockIdx.z == 1) { W = Wk; bias = bk; outp = ko;  vmode = 0; }
    else                      { W = Wv; bias = bv; outp = vto; vmode = 1; }

    const int tm = blockIdx.x * 128, tn = blockIdx.y * 128;
    f32x4 acc[4][4] = {};
    gemm_core(x, W, As, Bs, tm, tn, Ed, acc);

    const int tid = threadIdx.x, w = tid >> 6, lane = tid & 63;
    const int quad = lane >> 4, l15 = lane & 15;
    const int wy = w >> 1, wx = w & 1;
#pragma unroll
    for (int ni = 0; ni < 4; ++ni) {
        int gc = tn + wx * 64 + ni * 16 + l15;
        float bb = bias[gc];
        int h = gc >> 6, d = gc & 63;
#pragma unroll
        for (int mi = 0; mi < 4; ++mi) {
#pragma unroll
            for (int r = 0; r < 4; ++r) {
                int gr = tm + wy * 64 + mi * 16 + quad * 4 + r;
                int b_ = gr >> 11, s_ = gr & 2047;
                float v = acc[mi][ni][r] + bb;
                size_t addr;
                if (vmode == 0) addr = ((size_t)(b_ * Hh + h) * Ss + s_) * Dd + d;
                else            addr = ((size_t)(b_ * Hh + h) * Dd + d) * Ss + s_;
                outp[addr] = f2bf_hi(v);
            }
        }
    }
}

// Output projection: out = ctx @ Wo^T + bo, [M,E] FP32. Penalty fused in block (0,0).
__global__ __launch_bounds__(256, 3) void out_gemm(
    const ushort_t* __restrict__ ctx, const ushort_t* __restrict__ Wo,
    const float* __restrict__ bo, const float* __restrict__ z,
    float* __restrict__ out)
{
    __shared__ __align__(16) ushort_t As[128 * 64];
    __shared__ __align__(16) ushort_t Bs[64 * 64];
    const int tm = blockIdx.x * 128, tn = blockIdx.y * 64;

    const int tid  = threadIdx.x;
    const int w    = tid >> 6;
    const int lane = tid & 63;
    const int quad = lane >> 4;
    const int l15  = lane & 15;
    const int wy   = w >> 1, wx = w & 1;
    const int rowc = lane >> 3;
    const int col8 = (lane & 7) * 8;

    f32x4 acc[4][2] = {};
    for (int k0 = 0; k0 < Ed; k0 += 64) {
        __syncthreads();
#pragma unroll
        for (int i = 0; i < 4; ++i) {
            int chunk = w * 4 + i;
            int row = chunk * 8 + rowc;
            gld16(ctx + (size_t)(tm + row) * Ed + k0 + col8, (char*)As + chunk * 1024);
        }
#pragma unroll
        for (int i = 0; i < 2; ++i) {
            int chunk = w * 2 + i;
            int row = chunk * 8 + rowc;
            gld16(Wo + (size_t)(tn + row) * Ed + k0 + col8, (char*)Bs + chunk * 1024);
        }
        __syncthreads();
#pragma unroll
        for (int ks = 0; ks < 64; ks += 32) {
            bf16x8 a[4], b[2];
#pragma unroll
            for (int mi = 0; mi < 4; ++mi)
                a[mi] = *(const bf16x8*)&As[(wy * 64 + mi * 16 + l15) * 64 + ks + quad * 8];
#pragma unroll
            for (int ni = 0; ni < 2; ++ni)
                b[ni] = *(const bf16x8*)&Bs[(wx * 32 + ni * 16 + l15) * 64 + ks + quad * 8];
#pragma unroll
            for (int mi = 0; mi < 4; ++mi)
#pragma unroll
                for (int ni = 0; ni < 2; ++ni)
                    acc[mi][ni] = __builtin_amdgcn_mfma_f32_16x16x32_bf16(
                        a[mi], b[ni], acc[mi][ni], 0, 0, 0);
        }
    }

#pragma unroll
    for (int ni = 0; ni < 2; ++ni) {
        int gc = tn + wx * 32 + ni * 16 + l15;
        float bb = bo[gc];
#pragma unroll
        for (int mi = 0; mi < 4; ++mi)
#pragma unroll
            for (int r = 0; r < 4; ++r) {
                int gr = tm + wy * 64 + mi * 16 + quad * 4 + r;
                out[(size_t)gr * Ed + gc] = acc[mi][ni][r] + bb;
            }
    }

    if (blockIdx.x == 0 && blockIdx.y == 0 && tid == 0) {
        float s = 0.f;
        for (int hh = 0; hh < Hh; ++hh) s += 1.f / (1.f + __expf(-z[hh]));
        out[(size_t)Mm * Ed] = s * 0.01f;
    }
}

// Flash attention v17: R14 geometry + issue-early/drain-late pipeline.
// K double-buffered (prefetch kt+1 right after barrier A); V single-buffered,
// staged at iter top, drained only at barrier B after QK^T+softmax (~600cyc
// overlap). Softmax moved before barrier B (Ps is per-wave). Raw v_exp_f32.
// LDS: Ks 16KB + Vs 8KB + Ps 8.7KB = 33.3KB -> 4 blocks/CU.
// grid = (S/64, B*H) = (32, 32).
__global__ __launch_bounds__(256, 4) void attn(
    const ushort_t* __restrict__ Q, const ushort_t* __restrict__ Kk,
    const ushort_t* __restrict__ Vt, const float* __restrict__ z,
    ushort_t* __restrict__ ctx)
{
    __shared__ __align__(16) ushort_t Ks[2][64 * 64];  // swizzled [key][d], dbuf
    __shared__ __align__(16) ushort_t Vs[64 * 64];     // swizzled [d][key]
    __shared__ __align__(16) ushort_t Ps[4][16 * 68];  // per-wave P scratch

    const int tid = threadIdx.x, w = tid >> 6, lane = tid & 63;
    const int quad = lane >> 4, l15 = lane & 15;
    const int qt = blockIdx.x;           // 0..31
    const int bh = blockIdx.y;           // 0..31
    const int h = bh & (Hh - 1), b_ = bh >> 4;
    const size_t base = (size_t)bh * Ss * Dd;

    const float gate = 1.f / (1.f + __expf(-z[h]));
    const float scl2 = gate * 0.125f * 1.44269504f;  // gate/sqrt(D) * log2(e)

    bf16x8 aQ[2];
#pragma unroll
    for (int c = 0; c < 2; ++c)
        aQ[c] = *(const bf16x8*)&Q[base + (size_t)(qt * 64 + w * 16 + l15) * Dd
                                   + c * 32 + quad * 8];

    // Swizzled staging addresses (R11/R14 pattern)
    const int rowA = w * 16 + (lane >> 3);
    const int rowB = rowA + 8;
    const int gsA  = (lane & 7) ^ (rowA & 7);
    const int gsB  = (lane & 7) ^ (rowB & 7);
    const ushort_t* kSrcA = Kk + base + (size_t)rowA * Dd + gsA * 8;
    const ushort_t* kSrcB = Kk + base + (size_t)rowB * Dd + gsB * 8;
    const ushort_t* vSrcA = Vt + base + (size_t)rowA * Ss + gsA * 8;
    const ushort_t* vSrcB = Vt + base + (size_t)rowB * Ss + gsB * 8;
    ushort_t* vDstA = Vs + (w * 2) * 512;
    ushort_t* vDstB = Vs + (w * 2 + 1) * 512;

    f32x4 accO[4] = {};
    float lsum[4] = {0.f, 0.f, 0.f, 0.f};

    const int swq = (l15 & 7) * 8;

    // prologue: stage K(0) into Ks[0]
    gld16(kSrcA, &Ks[0][(w * 2) * 512]);
    gld16(kSrcB, &Ks[0][(w * 2 + 1) * 512]);

    for (int kt = 0; kt < Ss / 64; ++kt) {
        const int cur = kt & 1, nxt = cur ^ 1;
        __syncthreads();   // A: K(kt) visible (drained at prior B / prologue path);
                           //    all waves done reading Vs(kt-1), Ks[nxt](kt-1)
        if (kt + 1 < Ss / 64) {   // prefetch K(kt+1)
            gld16(kSrcA + (size_t)(kt + 1) * 64 * Dd, &Ks[nxt][(w * 2) * 512]);
            gld16(kSrcB + (size_t)(kt + 1) * 64 * Dd, &Ks[nxt][(w * 2 + 1) * 512]);
        }
        gld16(vSrcA + kt * 64, vDstA);   // V(kt): ~QK^T+softmax to land
        gld16(vSrcB + kt * 64, vDstB);

        // S = Q K^T on Ks[cur]
        f32x4 sAcc[4] = {};
#pragma unroll
        for (int ni = 0; ni < 4; ++ni) {
            bf16x8 b0 = *(const bf16x8*)&Ks[cur][(ni * 16 + l15) * 64 + ((quad * 8) ^ swq)];
            bf16x8 b1 = *(const bf16x8*)&Ks[cur][(ni * 16 + l15) * 64 + (((quad + 4) * 8) ^ swq)];
            sAcc[ni] = __builtin_amdgcn_mfma_f32_16x16x32_bf16(aQ[0], b0, sAcc[ni], 0, 0, 0);
            sAcc[ni] = __builtin_amdgcn_mfma_f32_16x16x32_bf16(aQ[1], b1, sAcc[ni], 0, 0, 0);
        }

        // softmax (per-wave; before barrier B to lengthen load overlap)
#pragma unroll
        for (int ni = 0; ni < 4; ++ni)
#pragma unroll
            for (int r = 0; r < 4; ++r) {
                float p = fast_exp2(sAcc[ni][r] * scl2);
                lsum[r] += p;
                Ps[w][(quad * 4 + r) * 68 + ni * 16 + l15] = f2bf_hi(p);
            }

        __syncthreads();   // B: Vs(kt) visible; drains V + K-prefetch (both issued early)

        // O += P V
#pragma unroll
        for (int c = 0; c < 2; ++c) {
            bf16x8 aP = *(const bf16x8*)&Ps[w][l15 * 68 + c * 32 + quad * 8];
#pragma unroll
            for (int ni = 0; ni < 4; ++ni) {
                bf16x8 bV = *(const bf16x8*)&Vs[(ni * 16 + l15) * 64 + (((quad + 4 * c) * 8) ^ swq)];
                accO[ni] = __builtin_amdgcn_mfma_f32_16x16x32_bf16(aP, bV, accO[ni], 0, 0, 0);
            }
        }
    }

#pragma unroll
    for (int r = 0; r < 4; ++r) {
        lsum[r] += __shfl_xor(lsum[r], 1);
        lsum[r] += __shfl_xor(lsum[r], 2);
        lsum[r] += __shfl_xor(lsum[r], 4);
        lsum[r] += __shfl_xor(lsum[r], 8);
    }

#pragma unroll
    for (int r = 0; r < 4; ++r) {
        int srow = qt * 64 + w * 16 + quad * 4 + r;
        float inv = 1.f / lsum[r];
#pragma unroll
        for (int ni = 0; ni < 4; ++ni) {
            int d = ni * 16 + l15;
            ctx[((size_t)(b_ * Ss + srow)) * Ed + h * Dd + d] = f2bf_hi(accO[ni][r] * inv);
        }
    }
}

extern "C" void kernel_launch(void* const* d_in, const int* in_sizes, int n_in,
                              void* d_out, int out_size, void* d_ws, size_t ws_size,
                              hipStream_t stream) {
    const float* x  = (const float*)d_in[0];
    const float* Wq = (const float*)d_in[1];
    const float* bq = (const float*)d_in[2];
    const float* Wk = (const float*)d_in[3];
    const float* bk = (const float*)d_in[4];
    const float* Wv = (const float*)d_in[5];
    const float* bv = (const float*)d_in[6];
    const float* Wo = (const float*)d_in[7];
    const float* bo = (const float*)d_in[8];
    const float* z  = (const float*)d_in[9];
    float* out = (float*)d_out;

    ushort_t* xb  = (ushort_t*)d_ws;              // [M,E]     8 MB
    ushort_t* Wqb = xb  + (size_t)Mm * Ed;        // [E,E]     2 MB
    ushort_t* Wkb = Wqb + (size_t)Ed * Ed;
    ushort_t* Wvb = Wkb + (size_t)Ed * Ed;
    ushort_t* Wob = Wvb + (size_t)Ed * Ed;
    ushort_t* qw  = Wob + (size_t)Ed * Ed;        // [B,H,S,D] 8 MB
    ushort_t* kw  = qw + (size_t)Mm * Ed;         // [B,H,S,D] 8 MB
    ushort_t* vT  = kw + (size_t)Mm * Ed;         // [B,H,D,S] 8 MB
    ushort_t* cx  = vT + (size_t)Mm * Ed;         // [B,S,E]   8 MB

    dim3 blk(256);
    cvt_all<<<dim3((NX4 + 4 * NW4) / 256), blk, 0, stream>>>(
        x, Wq, Wk, Wv, Wo, xb, Wqb, Wkb, Wvb, Wob);
    qkv_gemm<<<dim3(Mm / 128, Ed / 128, 3), blk, 0, stream>>>(
        xb, Wqb, bq, Wkb, bk, Wvb, bv, qw, kw, vT);
    attn<<<dim3(Ss / 64, 2 * Hh), blk, 0, stream>>>(qw, kw, vT, z, cx);
    out_gemm<<<dim3(Mm / 128, Ed / 64), blk, 0, stream>>>(cx, Wob, bo, z, out);
}

// Round 18
// 207.506 us; speedup vs baseline: 1.4293x; 1.0346x over previous
//
#include <hip/hip_runtime.h>

typedef unsigned short ushort_t;
typedef __bf16 bf16x8 __attribute__((ext_vector_type(8)));
typedef ushort_t u16x8 __attribute__((ext_vector_type(8)));
typedef float f32x4 __attribute__((ext_vector_type(4)));

#define DEVI __device__ __forceinline__

// Problem dims
constexpr int Ed = 1024;   // embed
constexpr int Hh = 16;     // heads
constexpr int Dd = 64;     // head dim
constexpr int Ss = 2048;   // seq
constexpr int Mm = 4096;   // B*S rows

constexpr int NX4 = Mm * Ed / 4;
constexpr int NW4 = Ed * Ed / 4;

DEVI ushort_t f2bf(float f) {      // RNE (cold paths only)
    union { float f; unsigned int i; } v; v.f = f;
    unsigned int r = v.i + 0x7fffu + ((v.i >> 16) & 1u);
    return (ushort_t)(r >> 16);
}
DEVI ushort_t f2bf_hi(float f) {   // truncation: compiles to *_d16_hi store, 0 VALU
    union { float f; unsigned int i; } v; v.f = f;
    return (ushort_t)(v.i >> 16);
}
DEVI float fast_exp2(float x) {    // raw v_exp_f32 (no ocml wrapper)
    float r;
    asm("v_exp_f32 %0, %1" : "=v"(r) : "v"(x));
    return r;
}

// One-shot fp32 -> bf16 conversion of x + 4 weight matrices (RNE).
__global__ __launch_bounds__(256) void cvt_all(
    const float* __restrict__ x,  const float* __restrict__ Wq,
    const float* __restrict__ Wk, const float* __restrict__ Wv,
    const float* __restrict__ Wo,
    ushort_t* __restrict__ xb,  ushort_t* __restrict__ Wqb,
    ushort_t* __restrict__ Wkb, ushort_t* __restrict__ Wvb,
    ushort_t* __restrict__ Wob)
{
    int i = blockIdx.x * 256 + threadIdx.x;
    const float* s; ushort_t* d; int off;
    if (i < NX4)                { s = x;  d = xb;  off = i; }
    else if (i < NX4 + NW4)     { s = Wq; d = Wqb; off = i - NX4; }
    else if (i < NX4 + 2 * NW4) { s = Wk; d = Wkb; off = i - NX4 - NW4; }
    else if (i < NX4 + 3 * NW4) { s = Wv; d = Wvb; off = i - NX4 - 2 * NW4; }
    else                        { s = Wo; d = Wob; off = i - NX4 - 3 * NW4; }
    float4 v = ((const float4*)s)[off];
    ushort4 o; o.x = f2bf(v.x); o.y = f2bf(v.y); o.z = f2bf(v.z); o.w = f2bf(v.w);
    ((ushort4*)d)[off] = o;
}

// async global->LDS, 16B per lane
DEVI void gld16(const void* g, void* l) {
    __builtin_amdgcn_global_load_lds(
        (__attribute__((address_space(1))) void*)(g),
        (__attribute__((address_space(3))) void*)(l), 16, 0, 0);
}

// ---------------- NT GEMM core (m97 pattern + XOR-swizzled LDS) ------------
// LDS slot (row, g) holds source granule g^(row&7); fragment-read granule
// = (quad + 4*(ks/32)) ^ (l15&7) -> 2 lanes/bank = conflict-free (m136).
// (Unswizzled m97 layout has row-stride 128B = 32 banks -> 16-way read
//  conflicts, m98's 1.7e7 SQ_LDS_BANK_CONFLICT.)
DEVI void gemm_core(const ushort_t* __restrict__ A, const ushort_t* __restrict__ W,
                    ushort_t* As, ushort_t* Bs, int tm, int tn, int K,
                    f32x4 acc[4][4])
{
    const int tid  = threadIdx.x;
    const int w    = tid >> 6;
    const int lane = tid & 63;
    const int quad = lane >> 4;
    const int l15  = lane & 15;
    const int wy   = w >> 1, wx = w & 1;
    const int rowc = lane >> 3;                      // row within 8-row chunk
    const int col8s = (((lane & 7) ^ rowc) * 8);     // swizzled source granule
    const int swq  = l15 & 7;                        // read-swizzle row term

    for (int k0 = 0; k0 < K; k0 += 64) {
        __syncthreads();
#pragma unroll
        for (int i = 0; i < 4; ++i) {
            int chunk = w * 4 + i;
            int row = chunk * 8 + rowc;              // row&7 == rowc
            gld16(A + (size_t)(tm + row) * K + k0 + col8s, (char*)As + chunk * 1024);
            gld16(W + (size_t)(tn + row) * K + k0 + col8s, (char*)Bs + chunk * 1024);
        }
        __syncthreads();
#pragma unroll
        for (int ks = 0; ks < 64; ks += 32) {
            const int k4 = ks >> 3;                  // 0 or 4
            bf16x8 a[4], b[4];
#pragma unroll
            for (int mi = 0; mi < 4; ++mi)
                a[mi] = *(const bf16x8*)&As[(wy * 64 + mi * 16 + l15) * 64
                                            + (((quad + k4) ^ swq) * 8)];
#pragma unroll
            for (int ni = 0; ni < 4; ++ni)
                b[ni] = *(const bf16x8*)&Bs[(wx * 64 + ni * 16 + l15) * 64
                                            + (((quad + k4) ^ swq) * 8)];
#pragma unroll
            for (int mi = 0; mi < 4; ++mi)
#pragma unroll
                for (int ni = 0; ni < 4; ++ni)
                    acc[mi][ni] = __builtin_amdgcn_mfma_f32_16x16x32_bf16(
                        a[mi], b[ni], acc[mi][ni], 0, 0, 0);
        }
    }
}

// Fused QKV projection. Q,K stored [B,H,S,D]; V stored [B,H,D,S].
__global__ __launch_bounds__(256, 3) void qkv_gemm(
    const ushort_t* __restrict__ x,
    const ushort_t* __restrict__ Wq, const float* __restrict__ bq,
    const ushort_t* __restrict__ Wk, const float* __restrict__ bk,
    const ushort_t* __restrict__ Wv, const float* __restrict__ bv,
    ushort_t* __restrict__ qo, ushort_t* __restrict__ ko, ushort_t* __restrict__ vto)
{
    __shared__ __align__(16) ushort_t As[128 * 64];
    __shared__ __align__(16) ushort_t Bs[128 * 64];
    const ushort_t* W; const float* bias; ushort_t* outp; int vmode;
    if (blockIdx.z == 0)      { W = Wq; bias = bq; outp = qo;  vmode = 0; }
    else if (blockIdx.z == 1) { W = Wk; bias = bk; outp = ko;  vmode = 0; }
    else                      { W = Wv; bias = bv; outp = vto; vmode = 1; }

    const int tm = blockIdx.x * 128, tn = blockIdx.y * 128;
    f32x4 acc[4][4] = {};
    gemm_core(x, W, As, Bs, tm, tn, Ed, acc);

    const int tid = threadIdx.x, w = tid >> 6, lane = tid & 63;
    const int quad = lane >> 4, l15 = lane & 15;
    const int wy = w >> 1, wx = w & 1;
#pragma unroll
    for (int ni = 0; ni < 4; ++ni) {
        int gc = tn + wx * 64 + ni * 16 + l15;
        float bb = bias[gc];
        int h = gc >> 6, d = gc & 63;
#pragma unroll
        for (int mi = 0; mi < 4; ++mi) {
#pragma unroll
            for (int r = 0; r < 4; ++r) {
                int gr = tm + wy * 64 + mi * 16 + quad * 4 + r;
                int b_ = gr >> 11, s_ = gr & 2047;
                float v = acc[mi][ni][r] + bb;
                size_t addr;
                if (vmode == 0) addr = ((size_t)(b_ * Hh + h) * Ss + s_) * Dd + d;
                else            addr = ((size_t)(b_ * Hh + h) * Dd + d) * Ss + s_;
                outp[addr] = f2bf_hi(v);
            }
        }
    }
}

// Output projection: out = ctx @ Wo^T + bo, [M,E] FP32. Penalty fused in block (0,0).
// 128x64 tile, grid (32,16) = 512 blocks = 2/CU. Swizzled LDS as gemm_core.
__global__ __launch_bounds__(256, 3) void out_gemm(
    const ushort_t* __restrict__ ctx, const ushort_t* __restrict__ Wo,
    const float* __restrict__ bo, const float* __restrict__ z,
    float* __restrict__ out)
{
    __shared__ __align__(16) ushort_t As[128 * 64];
    __shared__ __align__(16) ushort_t Bs[64 * 64];
    const int tm = blockIdx.x * 128, tn = blockIdx.y * 64;

    const int tid  = threadIdx.x;
    const int w    = tid >> 6;
    const int lane = tid & 63;
    const int quad = lane >> 4;
    const int l15  = lane & 15;
    const int wy   = w >> 1, wx = w & 1;
    const int rowc = lane >> 3;
    const int col8s = (((lane & 7) ^ rowc) * 8);
    const int swq  = l15 & 7;

    f32x4 acc[4][2] = {};
    for (int k0 = 0; k0 < Ed; k0 += 64) {
        __syncthreads();
#pragma unroll
        for (int i = 0; i < 4; ++i) {
            int chunk = w * 4 + i;
            int row = chunk * 8 + rowc;
            gld16(ctx + (size_t)(tm + row) * Ed + k0 + col8s, (char*)As + chunk * 1024);
        }
#pragma unroll
        for (int i = 0; i < 2; ++i) {
            int chunk = w * 2 + i;
            int row = chunk * 8 + rowc;
            gld16(Wo + (size_t)(tn + row) * Ed + k0 + col8s, (char*)Bs + chunk * 1024);
        }
        __syncthreads();
#pragma unroll
        for (int ks = 0; ks < 64; ks += 32) {
            const int k4 = ks >> 3;
            bf16x8 a[4], b[2];
#pragma unroll
            for (int mi = 0; mi < 4; ++mi)
                a[mi] = *(const bf16x8*)&As[(wy * 64 + mi * 16 + l15) * 64
                                            + (((quad + k4) ^ swq) * 8)];
#pragma unroll
            for (int ni = 0; ni < 2; ++ni)
                b[ni] = *(const bf16x8*)&Bs[(wx * 32 + ni * 16 + l15) * 64
                                            + (((quad + k4) ^ swq) * 8)];
#pragma unroll
            for (int mi = 0; mi < 4; ++mi)
#pragma unroll
                for (int ni = 0; ni < 2; ++ni)
                    acc[mi][ni] = __builtin_amdgcn_mfma_f32_16x16x32_bf16(
                        a[mi], b[ni], acc[mi][ni], 0, 0, 0);
        }
    }

#pragma unroll
    for (int ni = 0; ni < 2; ++ni) {
        int gc = tn + wx * 32 + ni * 16 + l15;
        float bb = bo[gc];
#pragma unroll
        for (int mi = 0; mi < 4; ++mi)
#pragma unroll
            for (int r = 0; r < 4; ++r) {
                int gr = tm + wy * 64 + mi * 16 + quad * 4 + r;
                out[(size_t)gr * Ed + gc] = acc[mi][ni][r] + bb;
            }
    }

    if (blockIdx.x == 0 && blockIdx.y == 0 && tid == 0) {
        float s = 0.f;
        for (int hh = 0; hh < Hh; ++hh) s += 1.f / (1.f + __expf(-z[hh]));
        out[(size_t)Mm * Ed] = s * 0.01f;
    }
}

// Flash attention v17 (frozen): K dbuf, issue-early/drain-late, swizzled LDS,
// no online max, raw v_exp, trunc d16_hi stores. grid = (S/64, B*H).
__global__ __launch_bounds__(256, 4) void attn(
    const ushort_t* __restrict__ Q, const ushort_t* __restrict__ Kk,
    const ushort_t* __restrict__ Vt, const float* __restrict__ z,
    ushort_t* __restrict__ ctx)
{
    __shared__ __align__(16) ushort_t Ks[2][64 * 64];  // swizzled [key][d], dbuf
    __shared__ __align__(16) ushort_t Vs[64 * 64];     // swizzled [d][key]
    __shared__ __align__(16) ushort_t Ps[4][16 * 68];  // per-wave P scratch

    const int tid = threadIdx.x, w = tid >> 6, lane = tid & 63;
    const int quad = lane >> 4, l15 = lane & 15;
    const int qt = blockIdx.x;           // 0..31
    const int bh = blockIdx.y;           // 0..31
    const int h = bh & (Hh - 1), b_ = bh >> 4;
    const size_t base = (size_t)bh * Ss * Dd;

    const float gate = 1.f / (1.f + __expf(-z[h]));
    const float scl2 = gate * 0.125f * 1.44269504f;  // gate/sqrt(D) * log2(e)

    bf16x8 aQ[2];
#pragma unroll
    for (int c = 0; c < 2; ++c)
        aQ[c] = *(const bf16x8*)&Q[base + (size_t)(qt * 64 + w * 16 + l15) * Dd
                                   + c * 32 + quad * 8];

    const int rowA = w * 16 + (lane >> 3);
    const int rowB = rowA + 8;
    const int gsA  = (lane & 7) ^ (rowA & 7);
    const int gsB  = (lane & 7) ^ (rowB & 7);
    const ushort_t* kSrcA = Kk + base + (size_t)rowA * Dd + gsA * 8;
    const ushort_t* kSrcB = Kk + base + (size_t)rowB * Dd + gsB * 8;
    const ushort_t* vSrcA = Vt + base + (size_t)rowA * Ss + gsA * 8;
    const ushort_t* vSrcB = Vt + base + (size_t)rowB * Ss + gsB * 8;
    ushort_t* vDstA = Vs + (w * 2) * 512;
    ushort_t* vDstB = Vs + (w * 2 + 1) * 512;

    f32x4 accO[4] = {};
    float lsum[4] = {0.f, 0.f, 0.f, 0.f};

    const int swq = (l15 & 7) * 8;

    // prologue: stage K(0) into Ks[0]
    gld16(kSrcA, &Ks[0][(w * 2) * 512]);
    gld16(kSrcB, &Ks[0][(w * 2 + 1) * 512]);

    for (int kt = 0; kt < Ss / 64; ++kt) {
        const int cur = kt & 1, nxt = cur ^ 1;
        __syncthreads();   // A: K(kt) visible; all waves done with Vs(kt-1), Ks[nxt]
        if (kt + 1 < Ss / 64) {   // prefetch K(kt+1)
            gld16(kSrcA + (size_t)(kt + 1) * 64 * Dd, &Ks[nxt][(w * 2) * 512]);
            gld16(kSrcB + (size_t)(kt + 1) * 64 * Dd, &Ks[nxt][(w * 2 + 1) * 512]);
        }
        gld16(vSrcA + kt * 64, vDstA);   // V(kt): QK^T+softmax to land
        gld16(vSrcB + kt * 64, vDstB);

        // S = Q K^T on Ks[cur]
        f32x4 sAcc[4] = {};
#pragma unroll
        for (int ni = 0; ni < 4; ++ni) {
            bf16x8 b0 = *(const bf16x8*)&Ks[cur][(ni * 16 + l15) * 64 + ((quad * 8) ^ swq)];
            bf16x8 b1 = *(const bf16x8*)&Ks[cur][(ni * 16 + l15) * 64 + (((quad + 4) * 8) ^ swq)];
            sAcc[ni] = __builtin_amdgcn_mfma_f32_16x16x32_bf16(aQ[0], b0, sAcc[ni], 0, 0, 0);
            sAcc[ni] = __builtin_amdgcn_mfma_f32_16x16x32_bf16(aQ[1], b1, sAcc[ni], 0, 0, 0);
        }

        // softmax (per-wave; before barrier B to lengthen load overlap)
#pragma unroll
        for (int ni = 0; ni < 4; ++ni)
#pragma unroll
            for (int r = 0; r < 4; ++r) {
                float p = fast_exp2(sAcc[ni][r] * scl2);
                lsum[r] += p;
                Ps[w][(quad * 4 + r) * 68 + ni * 16 + l15] = f2bf_hi(p);
            }

        __syncthreads();   // B: Vs(kt) visible; drains V + K-prefetch

        // O += P V
#pragma unroll
        for (int c = 0; c < 2; ++c) {
            bf16x8 aP = *(const bf16x8*)&Ps[w][l15 * 68 + c * 32 + quad * 8];
#pragma unroll
            for (int ni = 0; ni < 4; ++ni) {
                bf16x8 bV = *(const bf16x8*)&Vs[(ni * 16 + l15) * 64 + (((quad + 4 * c) * 8) ^ swq)];
                accO[ni] = __builtin_amdgcn_mfma_f32_16x16x32_bf16(aP, bV, accO[ni], 0, 0, 0);
            }
        }
    }

#pragma unroll
    for (int r = 0; r < 4; ++r) {
        lsum[r] += __shfl_xor(lsum[r], 1);
        lsum[r] += __shfl_xor(lsum[r], 2);
        lsum[r] += __shfl_xor(lsum[r], 4);
        lsum[r] += __shfl_xor(lsum[r], 8);
    }

#pragma unroll
    for (int r = 0; r < 4; ++r) {
        int srow = qt * 64 + w * 16 + quad * 4 + r;
        float inv = 1.f / lsum[r];
#pragma unroll
        for (int ni = 0; ni < 4; ++ni) {
            int d = ni * 16 + l15;
            ctx[((size_t)(b_ * Ss + srow)) * Ed + h * Dd + d] = f2bf_hi(accO[ni][r] * inv);
        }
    }
}

extern "C" void kernel_launch(void* const* d_in, const int* in_sizes, int n_in,
                              void* d_out, int out_size, void* d_ws, size_t ws_size,
                              hipStream_t stream) {
    const float* x  = (const float*)d_in[0];
    const float* Wq = (const float*)d_in[1];
    const float* bq = (const float*)d_in[2];
    const float* Wk = (const float*)d_in[3];
    const float* bk = (const float*)d_in[4];
    const float* Wv = (const float*)d_in[5];
    const float* bv = (const float*)d_in[6];
    const float* Wo = (const float*)d_in[7];
    const float* bo = (const float*)d_in[8];
    const float* z  = (const float*)d_in[9];
    float* out = (float*)d_out;

    ushort_t* xb  = (ushort_t*)d_ws;              // [M,E]     8 MB
    ushort_t* Wqb = xb  + (size_t)Mm * Ed;        // [E,E]     2 MB
    ushort_t* Wkb = Wqb + (size_t)Ed * Ed;
    ushort_t* Wvb = Wkb + (size_t)Ed * Ed;
    ushort_t* Wob = Wvb + (size_t)Ed * Ed;
    ushort_t* qw  = Wob + (size_t)Ed * Ed;        // [B,H,S,D] 8 MB
    ushort_t* kw  = qw + (size_t)Mm * Ed;         // [B,H,S,D] 8 MB
    ushort_t* vT  = kw + (size_t)Mm * Ed;         // [B,H,D,S] 8 MB
    ushort_t* cx  = vT + (size_t)Mm * Ed;         // [B,S,E]   8 MB

    dim3 blk(256);
    cvt_all<<<dim3((NX4 + 4 * NW4) / 256), blk, 0, stream>>>(
        x, Wq, Wk, Wv, Wo, xb, Wqb, Wkb, Wvb, Wob);
    qkv_gemm<<<dim3(Mm / 128, Ed / 128, 3), blk, 0, stream>>>(
        xb, Wqb, bq, Wkb, bk, Wvb, bv, qw, kw, vT);
    attn<<<dim3(Ss / 64, 2 * Hh), blk, 0, stream>>>(qw, kw, vT, z, cx);
    out_gemm<<<dim3(Mm / 128, Ed / 64), blk, 0, stream>>>(cx, Wob, bo, z, out);
}